// Round 2
// baseline (371.621 us; speedup 1.0000x reference)
//
#include <hip/hip_runtime.h>
#include <stdint.h>

#define DIM 256
#define NEMB 8192
#define NTOK 16384
#define HW 1024

typedef __attribute__((ext_vector_type(8))) short short8;
typedef __attribute__((ext_vector_type(4))) float floatx4;

// ---- helpers ----
__device__ __forceinline__ unsigned short f2bf(float x) {
  unsigned int u = __float_as_uint(x);
  return (unsigned short)((u + 0x7fffu + ((u >> 16) & 1u)) >> 16);  // RN-even
}
__device__ __forceinline__ float bf2f(unsigned short b) {
  return __uint_as_float(((unsigned int)b) << 16);
}
// order-preserving float -> uint, packed with index for argmin w/ first-idx tie-break
__device__ __forceinline__ unsigned long long packscore(float s, unsigned int idx) {
  unsigned int u = __float_as_uint(s);
  u = (u & 0x80000000u) ? ~u : (u | 0x80000000u);
  return (((unsigned long long)u) << 32) | idx;
}
__device__ __forceinline__ void async_cp16(void* lds, const void* g) {
  __builtin_amdgcn_global_load_lds(
      (const __attribute__((address_space(1))) unsigned int*)g,
      (__attribute__((address_space(3))) unsigned int*)lds, 16, 0, 0);
}

// ---- kernel 1: split emb table into bf16 hi/lo + row sum-of-squares ----
__global__ __launch_bounds__(256) void prep_w_kernel(
    const float* __restrict__ emb, unsigned short* __restrict__ whi,
    unsigned short* __restrict__ wlo, float* __restrict__ wsq) {
  int lane = threadIdx.x & 63;
  int row = blockIdx.x * 4 + (threadIdx.x >> 6);
  const float4 v = *(const float4*)(emb + (size_t)row * DIM + lane * 4);
  float s = v.x * v.x + v.y * v.y + v.z * v.z + v.w * v.w;
  unsigned short h0 = f2bf(v.x), h1 = f2bf(v.y), h2 = f2bf(v.z), h3 = f2bf(v.w);
  ushort4 hv = make_ushort4(h0, h1, h2, h3);
  ushort4 lv = make_ushort4(f2bf(v.x - bf2f(h0)), f2bf(v.y - bf2f(h1)),
                            f2bf(v.z - bf2f(h2)), f2bf(v.w - bf2f(h3)));
  *(ushort4*)(whi + (size_t)row * DIM + lane * 4) = hv;
  *(ushort4*)(wlo + (size_t)row * DIM + lane * 4) = lv;
#pragma unroll
  for (int off = 32; off > 0; off >>= 1) s += __shfl_xor(s, off, 64);
  if (lane == 0) wsq[row] = s;
}

// ---- kernel 2: transpose z [B,D,HW] -> token-major [N,D] bf16 hi/lo ----
__global__ __launch_bounds__(256) void prep_z_kernel(
    const float* __restrict__ z, unsigned short* __restrict__ zhi,
    unsigned short* __restrict__ zlo) {
  __shared__ float tile[64][65];
  int b = blockIdx.x, d0 = blockIdx.y * 64, hw0 = blockIdx.z * 64;
  int lane = threadIdx.x & 63, grp = threadIdx.x >> 6;
  const float* src = z + (size_t)b * DIM * HW + hw0 + lane;
#pragma unroll
  for (int i = 0; i < 16; i++) {
    int dl = grp + i * 4;
    tile[dl][lane] = src[(size_t)(d0 + dl) * HW];  // coalesced along hw
  }
  __syncthreads();
#pragma unroll
  for (int p = 0; p < 16; p++) {
    int n = grp + p * 4;  // hw_local
    float x = tile[lane][n];  // lane indexes d now
    unsigned short h = f2bf(x);
    unsigned short lo = f2bf(x - bf2f(h));
    size_t off = (size_t)(b * HW + hw0 + n) * DIM + d0 + lane;  // coalesced along d
    zhi[off] = h;
    zlo[off] = lo;
  }
}

// ---- kernel 3: K=768 split-bf16 GEMM with fused per-chunk argmin ----
// logical K blocks kb=0..11 (64 each): Z src: kb0-7 -> zhi (cols (kb&3)*64), kb8-11 -> zlo
//                                      W src: kb0-3 whi, kb4-7 wlo, kb8-11 whi
__global__ __launch_bounds__(256) void gemm_argmin_kernel(
    const unsigned short* __restrict__ zhi, const unsigned short* __restrict__ zlo,
    const unsigned short* __restrict__ whi, const unsigned short* __restrict__ wlo,
    const float* __restrict__ wsq, unsigned long long* __restrict__ partials) {
  __shared__ __align__(16) unsigned short sA[128 * 64];
  __shared__ __align__(16) unsigned short sB[128 * 64];
  __shared__ unsigned long long red[2][128];

  const int kchunk = blockIdx.x;  // 0..63 embedding chunk of 128
  const int nb = blockIdx.y;      // 0..127 token chunk of 128
  const int n0 = nb * 128, k0 = kchunk * 128;
  const int tid = threadIdx.x;
  const int lane = tid & 63, wave = tid >> 6;
  const int wm = wave & 1, wn = wave >> 1;
  const int c = lane & 15, quad = lane >> 4;

  float wsq_r[4];
#pragma unroll
  for (int tn = 0; tn < 4; tn++) wsq_r[tn] = wsq[k0 + wn * 64 + tn * 16 + c];

  floatx4 acc[4][4] = {};

#pragma unroll
  for (int kb = 0; kb < 12; kb++) {
    const unsigned short* srcZ = (kb >= 8) ? zlo : zhi;
    const unsigned short* srcW = ((kb >> 2) == 1) ? wlo : whi;
    const int col = (kb & 3) * 64;
    // stage A (128 rows x 64 k, 16B chunks, XOR-swizzled within each 128B row)
#pragma unroll
    for (int j = 0; j < 4; j++) {
      int chunk = tid + j * 256;            // 0..1023
      int row = chunk >> 3;
      int cg = (chunk & 7) ^ (row & 7);     // global chunk for this LDS slot
      async_cp16(sA + chunk * 8, srcZ + (size_t)(n0 + row) * DIM + col + cg * 8);
    }
#pragma unroll
    for (int j = 0; j < 4; j++) {
      int chunk = tid + j * 256;
      int row = chunk >> 3;
      int cg = (chunk & 7) ^ (row & 7);
      async_cp16(sB + chunk * 8, srcW + (size_t)(k0 + row) * DIM + col + cg * 8);
    }
    __syncthreads();  // drains vmcnt for global_load_lds
#pragma unroll
    for (int s = 0; s < 2; s++) {  // two 32-wide k-steps
      short8 af[4], bf_[4];
#pragma unroll
      for (int t = 0; t < 4; t++) {
        int row = wm * 64 + t * 16 + c;
        int ch = (s * 4 + quad) ^ (row & 7);
        af[t] = *(const short8*)(sA + row * 64 + ch * 8);
      }
#pragma unroll
      for (int t = 0; t < 4; t++) {
        int row = wn * 64 + t * 16 + c;
        int ch = (s * 4 + quad) ^ (row & 7);
        bf_[t] = *(const short8*)(sB + row * 64 + ch * 8);
      }
#pragma unroll
      for (int tm = 0; tm < 4; tm++)
#pragma unroll
        for (int tn = 0; tn < 4; tn++)
          acc[tm][tn] = __builtin_amdgcn_mfma_f32_16x16x32_bf16(
              af[tm], bf_[tn], acc[tm][tn], 0, 0, 0);
    }
    __syncthreads();
  }

  // epilogue: score = wsq - 2*dot ; argmin over this block's 128 embeddings
  // C/D layout: col = lane&15 (emb), row = quad*4 + reg (token)   [m89]
#pragma unroll
  for (int tm = 0; tm < 4; tm++) {
#pragma unroll
    for (int r = 0; r < 4; r++) {
      unsigned long long p =
          packscore(wsq_r[0] - 2.0f * acc[tm][0][r], (unsigned)(k0 + wn * 64 + c));
#pragma unroll
      for (int tn = 1; tn < 4; tn++) {
        unsigned long long q = packscore(wsq_r[tn] - 2.0f * acc[tm][tn][r],
                                         (unsigned)(k0 + wn * 64 + tn * 16 + c));
        p = q < p ? q : p;
      }
#pragma unroll
      for (int off = 1; off < 16; off <<= 1) {  // min across the 16 emb-lanes
        unsigned long long o = __shfl_xor(p, off, 16);
        p = o < p ? o : p;
      }
      if (c == 0) red[wn][wm * 64 + tm * 16 + quad * 4 + r] = p;
    }
  }
  __syncthreads();
  if (tid < 128) {
    unsigned long long a = red[0][tid], b = red[1][tid];
    partials[(size_t)kchunk * NTOK + n0 + tid] = a < b ? a : b;  // coalesced
  }
}

// ---- kernel 4: top-2 of the 64 chunk minima per token -> candidate pair ----
__global__ __launch_bounds__(256) void reduce_top2_kernel(
    const unsigned long long* __restrict__ partials, int2* __restrict__ cand) {
  int t = blockIdx.x * 256 + threadIdx.x;
  unsigned long long m1 = ~0ULL, m2 = ~0ULL;
  for (int kb = 0; kb < 64; kb++) {
    unsigned long long v = partials[(size_t)kb * NTOK + t];
    if (v < m1) { m2 = m1; m1 = v; }
    else if (v < m2) { m2 = v; }
  }
  cand[t] = make_int2((int)(m1 & 0xffffffffULL), (int)(m2 & 0xffffffffULL));
}

// ---- kernel 5: exact double-precision rescore of the two candidates ----
// dist_k = ||w_k||^2 - 2 z.w_k  (z_sq argmin-invariant); one wave per token
__global__ __launch_bounds__(256) void rescore_kernel(
    const int2* __restrict__ cand, const float* __restrict__ z,
    const float* __restrict__ emb, int* __restrict__ ids) {
  int wave = threadIdx.x >> 6, lane = threadIdx.x & 63;
  int token = blockIdx.x * 4 + wave;
  int b = token >> 10, hw = token & (HW - 1);
  int2 cd = cand[token];
  const float* zb = z + (size_t)b * DIM * HW + hw;
  const float* e0 = emb + (size_t)cd.x * DIM;
  const float* e1 = emb + (size_t)cd.y * DIM;
  double s0 = 0.0, s1 = 0.0;
#pragma unroll
  for (int j = 0; j < 4; j++) {
    int d = lane + j * 64;
    double zv = (double)zb[(size_t)d * HW];
    double w0 = (double)e0[d], w1 = (double)e1[d];
    s0 += w0 * (w0 - 2.0 * zv);
    s1 += w1 * (w1 - 2.0 * zv);
  }
#pragma unroll
  for (int off = 32; off > 0; off >>= 1) {
    s0 += __shfl_xor(s0, off, 64);
    s1 += __shfl_xor(s1, off, 64);
  }
  if (lane == 0) {
    int pick;
    if (s0 < s1) pick = cd.x;
    else if (s1 < s0) pick = cd.y;
    else pick = cd.x < cd.y ? cd.x : cd.y;  // tie: lowest index (np argmin)
    ids[token] = pick;
  }
}

// ---- kernel 6: gather emb rows, transpose to [B,D,H,W] via LDS ----
__global__ __launch_bounds__(256) void gather_kernel(
    const int* __restrict__ ids, const float* __restrict__ emb,
    float* __restrict__ out) {
  __shared__ float tile[32][257];
  __shared__ int sid[32];
  int b = blockIdx.x;
  int hw0 = blockIdx.y * 32;
  int tid = threadIdx.x;
  if (tid < 32) sid[tid] = ids[b * HW + hw0 + tid];
  __syncthreads();
  for (int i = 0; i < 32; i++)
    tile[i][tid] = emb[(size_t)sid[i] * DIM + tid];  // coalesced 1KB row loads
  __syncthreads();
  int h = tid & 31, dg = tid >> 5;
  for (int i = 0; i < 32; i++) {
    int d = i * 8 + dg;
    out[(size_t)b * DIM * HW + (size_t)d * HW + hw0 + h] = tile[h][d];  // 128B segs
  }
}

extern "C" void kernel_launch(void* const* d_in, const int* in_sizes, int n_in,
                              void* d_out, int out_size, void* d_ws, size_t ws_size,
                              hipStream_t stream) {
  const float* z = (const float*)d_in[0];     // [16,256,32,32]
  const float* emb = (const float*)d_in[1];   // [8192,256]
  float* out = (float*)d_out;
  char* ws = (char*)d_ws;

  // zhi/zlo live in d_out (16 MB) — dead until gather fully overwrites it.
  unsigned short* zhi = (unsigned short*)d_out;
  unsigned short* zlo = (unsigned short*)((char*)d_out + 8388608);

  // ws layout (bytes): whi 4M | wlo 4M | wsq 32K | partials 8M | cand 128K | ids 64K
  unsigned short* whi = (unsigned short*)(ws);
  unsigned short* wlo = (unsigned short*)(ws + 4194304);
  float* wsq = (float*)(ws + 8388608);
  unsigned long long* partials = (unsigned long long*)(ws + 8421376);
  int2* cand = (int2*)(ws + 16809984);
  int* ids = (int*)(ws + 16941056);

  prep_w_kernel<<<dim3(2048), 256, 0, stream>>>(emb, whi, wlo, wsq);
  prep_z_kernel<<<dim3(16, 4, 16), 256, 0, stream>>>(z, zhi, zlo);
  gemm_argmin_kernel<<<dim3(64, 128), 256, 0, stream>>>(zhi, zlo, whi, wlo, wsq, partials);
  reduce_top2_kernel<<<dim3(64), 256, 0, stream>>>(partials, cand);
  rescore_kernel<<<dim3(4096), 256, 0, stream>>>(cand, z, emb, ids);
  gather_kernel<<<dim3(16, 32), 256, 0, stream>>>(ids, emb, out);
}

// Round 3
// 351.271 us; speedup vs baseline: 1.0579x; 1.0579x over previous
//
#include <hip/hip_runtime.h>
#include <stdint.h>

#define DIM 256
#define NEMB 8192
#define NTOK 16384
#define HW 1024

typedef __attribute__((ext_vector_type(4))) int int4v;

// ---- helpers ----
// order-preserving float -> uint, packed with index for argmin w/ first-idx tie-break
__device__ __forceinline__ unsigned long long packscore(float s, unsigned int idx) {
  unsigned int u = __float_as_uint(s);
  u = (u & 0x80000000u) ? ~u : (u | 0x80000000u);
  return (((unsigned long long)u) << 32) | idx;
}
__device__ __forceinline__ void async_cp16(void* lds, const void* g) {
  __builtin_amdgcn_global_load_lds(
      (const __attribute__((address_space(1))) unsigned int*)g,
      (__attribute__((address_space(3))) unsigned int*)lds, 16, 0, 0);
}
// x ~ s*(q0 + q1/128), s = 1/20
__device__ __forceinline__ int q0_of(float x) {
  int q = __float2int_rn(x * 20.0f);
  return q > 127 ? 127 : (q < -127 ? -127 : q);
}
__device__ __forceinline__ int q1_of(float x, int q0) {
  float e = x * 20.0f - (float)q0;
  int q = __float2int_rn(e * 128.0f);
  return q > 127 ? 127 : (q < -127 ? -127 : q);
}
__device__ __forceinline__ unsigned int pack4(int a, int b, int c, int d) {
  return (unsigned int)(a & 0xff) | ((unsigned int)(b & 0xff) << 8) |
         ((unsigned int)(c & 0xff) << 16) | ((unsigned int)(d & 0xff) << 24);
}
// merge two sorted top-2 pairs
__device__ __forceinline__ void merge2(unsigned long long& m1, unsigned long long& m2,
                                       unsigned long long o1, unsigned long long o2) {
  if (o1 < m1) {
    m2 = (m1 < o2) ? m1 : o2;
    m1 = o1;
  } else {
    m2 = (m2 < o1) ? m2 : o1;
  }
}

// ---- kernel 1: quantize emb table to int8 q0/q1 + exact row sum-of-squares ----
__global__ __launch_bounds__(256) void prep_w_kernel(
    const float* __restrict__ emb, unsigned int* __restrict__ q0w,
    unsigned int* __restrict__ q1w, float* __restrict__ wsq) {
  int lane = threadIdx.x & 63;
  int row = blockIdx.x * 4 + (threadIdx.x >> 6);
  const float4 v = *(const float4*)(emb + (size_t)row * DIM + lane * 4);
  float s = v.x * v.x + v.y * v.y + v.z * v.z + v.w * v.w;
  int a0 = q0_of(v.x), b0 = q0_of(v.y), c0 = q0_of(v.z), d0 = q0_of(v.w);
  q0w[row * (DIM / 4) + lane] = pack4(a0, b0, c0, d0);
  q1w[row * (DIM / 4) + lane] =
      pack4(q1_of(v.x, a0), q1_of(v.y, b0), q1_of(v.z, c0), q1_of(v.w, d0));
#pragma unroll
  for (int off = 32; off > 0; off >>= 1) s += __shfl_xor(s, off, 64);
  if (lane == 0) wsq[row] = s;
}

// ---- kernel 2: transpose z [B,D,HW] -> token-major [N,D] int8 q0/q1 ----
__global__ __launch_bounds__(256) void prep_z_kernel(
    const float* __restrict__ z, unsigned int* __restrict__ q0z,
    unsigned int* __restrict__ q1z) {
  __shared__ float tile[64][65];
  int b = blockIdx.x, d0 = blockIdx.y * 64, hw0 = blockIdx.z * 64;
  int tid = threadIdx.x;
  int lane = tid & 63, grp = tid >> 6;
  const float* src = z + (size_t)b * DIM * HW + hw0 + lane;
#pragma unroll
  for (int i = 0; i < 16; i++) {
    int dl = grp + i * 4;
    tile[dl][lane] = src[(size_t)(d0 + dl) * HW];  // coalesced along hw
  }
  __syncthreads();
  int dq = tid & 15;  // covers 4 d's
#pragma unroll
  for (int p = 0; p < 4; p++) {
    int n = (tid >> 4) + p * 16;  // hw_local
    float x0 = tile[dq * 4 + 0][n], x1 = tile[dq * 4 + 1][n];
    float x2 = tile[dq * 4 + 2][n], x3 = tile[dq * 4 + 3][n];
    int a0 = q0_of(x0), b0 = q0_of(x1), c0 = q0_of(x2), e0 = q0_of(x3);
    size_t off = (size_t)(b * HW + hw0 + n) * (DIM / 4) + (d0 >> 2) + dq;
    q0z[off] = pack4(a0, b0, c0, e0);
    q1z[off] = pack4(q1_of(x0, a0), q1_of(x1, b0), q1_of(x2, c0), q1_of(x3, e0));
  }
}

// ---- kernel 3: int8 split GEMM (acc = 128*P00 + P01) + fused top-2 argmin ----
// iters (BK=128 bytes): 0-1: q0z*q0w ; <<7 ; 2-3: q0z*q1w ; 4-5: q1z*q0w
__global__ __launch_bounds__(256) void gemm_argmin_kernel(
    const signed char* __restrict__ q0z, const signed char* __restrict__ q1z,
    const signed char* __restrict__ q0w, const signed char* __restrict__ q1w,
    const float* __restrict__ wsq, unsigned long long* __restrict__ partials) {
  __shared__ __align__(16) signed char sA[128 * 128];
  __shared__ __align__(16) signed char sB[128 * 128];
  __shared__ unsigned long long red1[2][128];
  __shared__ unsigned long long red2[2][128];

  const int kchunk = blockIdx.x;  // 0..63 embedding chunk of 128
  const int nb = blockIdx.y;      // 0..127 token chunk of 128
  const int n0 = nb * 128, k0 = kchunk * 128;
  const int tid = threadIdx.x;
  const int lane = tid & 63, wave = tid >> 6;
  const int wm = wave & 1, wn = wave >> 1;
  const int c = lane & 15, quad = lane >> 4;

  float wsq_r[4];
#pragma unroll
  for (int tn = 0; tn < 4; tn++) wsq_r[tn] = wsq[k0 + wn * 64 + tn * 16 + c];

  int4v acc[4][4] = {};

#pragma unroll
  for (int it = 0; it < 6; it++) {
    const signed char* srcZ = (it < 4) ? q0z : q1z;
    const signed char* srcW = (it < 2) ? q0w : ((it < 4) ? q1w : q0w);
    const int col = (it & 1) * 128;
    // stage A/B: 128 rows x 128 bytes each, 16B chunks, XOR swizzle per row
#pragma unroll
    for (int j = 0; j < 4; j++) {
      int chunk = tid + j * 256;  // 0..1023
      int row = chunk >> 3;
      int cg = (chunk & 7) ^ (row & 7);
      async_cp16(sA + chunk * 16, srcZ + (size_t)(n0 + row) * DIM + col + cg * 16);
    }
#pragma unroll
    for (int j = 0; j < 4; j++) {
      int chunk = tid + j * 256;
      int row = chunk >> 3;
      int cg = (chunk & 7) ^ (row & 7);
      async_cp16(sB + chunk * 16, srcW + (size_t)(k0 + row) * DIM + col + cg * 16);
    }
    __syncthreads();  // drains vmcnt for global_load_lds
#pragma unroll
    for (int s = 0; s < 2; s++) {  // two K=64 steps
      int4v af[4], bf_[4];
#pragma unroll
      for (int t = 0; t < 4; t++) {
        int row = wm * 64 + t * 16 + c;
        int ch = (s * 4 + quad) ^ (row & 7);
        af[t] = *(const int4v*)(sA + row * 128 + ch * 16);
      }
#pragma unroll
      for (int t = 0; t < 4; t++) {
        int row = wn * 64 + t * 16 + c;
        int ch = (s * 4 + quad) ^ (row & 7);
        bf_[t] = *(const int4v*)(sB + row * 128 + ch * 16);
      }
#pragma unroll
      for (int tm = 0; tm < 4; tm++)
#pragma unroll
        for (int tn = 0; tn < 4; tn++)
          acc[tm][tn] = __builtin_amdgcn_mfma_i32_16x16x64_i8(
              af[tm], bf_[tn], acc[tm][tn], 0, 0, 0);
    }
    __syncthreads();
    if (it == 1) {  // acc = P00 -> 128*P00, then keep accumulating P01
#pragma unroll
      for (int tm = 0; tm < 4; tm++)
#pragma unroll
        for (int tn = 0; tn < 4; tn++) acc[tm][tn] = acc[tm][tn] << 7;
    }
  }

  // epilogue: score = wsq - acc*(2*s^2/128), s=1/20 -> 1/25600
  // C/D layout: col = lane&15 (code), row = quad*4 + reg (token)
  const float SC = 3.90625e-5f;
#pragma unroll
  for (int tm = 0; tm < 4; tm++) {
#pragma unroll
    for (int r = 0; r < 4; r++) {
      unsigned long long m1 = ~0ULL, m2 = ~0ULL;
#pragma unroll
      for (int tn = 0; tn < 4; tn++) {
        float sc = wsq_r[tn] - (float)acc[tm][tn][r] * SC;
        unsigned long long v =
            packscore(sc, (unsigned)(k0 + wn * 64 + tn * 16 + c));
        if (v < m1) { m2 = m1; m1 = v; }
        else if (v < m2) { m2 = v; }
      }
#pragma unroll
      for (int off = 1; off < 16; off <<= 1) {  // top-2 across the 16 code-lanes
        unsigned long long o1 = __shfl_xor(m1, off, 16);
        unsigned long long o2 = __shfl_xor(m2, off, 16);
        merge2(m1, m2, o1, o2);
      }
      if (c == 0) {
        int tok = wm * 64 + tm * 16 + quad * 4 + r;
        red1[wn][tok] = m1;
        red2[wn][tok] = m2;
      }
    }
  }
  __syncthreads();
  if (tid < 128) {
    unsigned long long m1 = red1[0][tid], m2 = red2[0][tid];
    merge2(m1, m2, red1[1][tid], red2[1][tid]);
    partials[(size_t)(kchunk * 2) * NTOK + n0 + tid] = m1;      // coalesced
    partials[(size_t)(kchunk * 2 + 1) * NTOK + n0 + tid] = m2;
  }
}

// ---- kernel 4: global top-2 over 64 chunks x 2 entries per token ----
__global__ __launch_bounds__(256) void reduce_top2_kernel(
    const unsigned long long* __restrict__ partials, int2* __restrict__ cand) {
  int t = blockIdx.x * 256 + threadIdx.x;
  unsigned long long m1 = ~0ULL, m2 = ~0ULL;
  for (int p = 0; p < 128; p++) {
    unsigned long long v = partials[(size_t)p * NTOK + t];
    if (v < m1) { m2 = m1; m1 = v; }
    else if (v < m2) { m2 = v; }
  }
  cand[t] = make_int2((int)(m1 & 0xffffffffULL), (int)(m2 & 0xffffffffULL));
}

// ---- kernel 5: exact double-precision rescore of the two candidates ----
__global__ __launch_bounds__(256) void rescore_kernel(
    const int2* __restrict__ cand, const float* __restrict__ z,
    const float* __restrict__ emb, int* __restrict__ ids) {
  int wave = threadIdx.x >> 6, lane = threadIdx.x & 63;
  int token = blockIdx.x * 4 + wave;
  int b = token >> 10, hw = token & (HW - 1);
  int2 cd = cand[token];
  const float* zb = z + (size_t)b * DIM * HW + hw;
  const float* e0 = emb + (size_t)cd.x * DIM;
  const float* e1 = emb + (size_t)cd.y * DIM;
  double s0 = 0.0, s1 = 0.0;
#pragma unroll
  for (int j = 0; j < 4; j++) {
    int d = lane + j * 64;
    double zv = (double)zb[(size_t)d * HW];
    double w0 = (double)e0[d], w1 = (double)e1[d];
    s0 += w0 * (w0 - 2.0 * zv);
    s1 += w1 * (w1 - 2.0 * zv);
  }
#pragma unroll
  for (int off = 32; off > 0; off >>= 1) {
    s0 += __shfl_xor(s0, off, 64);
    s1 += __shfl_xor(s1, off, 64);
  }
  if (lane == 0) {
    int pick;
    if (s0 < s1) pick = cd.x;
    else if (s1 < s0) pick = cd.y;
    else pick = cd.x < cd.y ? cd.x : cd.y;  // tie: lowest index (np argmin)
    ids[token] = pick;
  }
}

// ---- kernel 6: gather emb rows, transpose to [B,D,H,W] via LDS ----
__global__ __launch_bounds__(256) void gather_kernel(
    const int* __restrict__ ids, const float* __restrict__ emb,
    float* __restrict__ out) {
  __shared__ float tile[32][257];
  __shared__ int sid[32];
  int b = blockIdx.x;
  int hw0 = blockIdx.y * 32;
  int tid = threadIdx.x;
  if (tid < 32) sid[tid] = ids[b * HW + hw0 + tid];
  __syncthreads();
  for (int i = 0; i < 32; i++)
    tile[i][tid] = emb[(size_t)sid[i] * DIM + tid];  // coalesced 1KB row loads
  __syncthreads();
  int h = tid & 31, dg = tid >> 5;
  for (int i = 0; i < 32; i++) {
    int d = i * 8 + dg;
    out[(size_t)b * DIM * HW + (size_t)d * HW + hw0 + h] = tile[h][d];  // 128B segs
  }
}

extern "C" void kernel_launch(void* const* d_in, const int* in_sizes, int n_in,
                              void* d_out, int out_size, void* d_ws, size_t ws_size,
                              hipStream_t stream) {
  const float* z = (const float*)d_in[0];     // [16,256,32,32]
  const float* emb = (const float*)d_in[1];   // [8192,256]
  float* out = (float*)d_out;
  char* ws = (char*)d_ws;

  // q0z/q1z live in d_out (16 MB) — dead until gather fully overwrites it.
  signed char* q0z = (signed char*)d_out;
  signed char* q1z = (signed char*)((char*)d_out + 4194304);

  // ws layout: q0w 2M | q1w 2M | wsq 32K | partials 16M | cand 128K | ids 64K
  signed char* q0w = (signed char*)(ws);
  signed char* q1w = (signed char*)(ws + 2097152);
  float* wsq = (float*)(ws + 4194304);
  unsigned long long* partials = (unsigned long long*)(ws + 4227072);
  int2* cand = (int2*)(ws + 21004288);
  int* ids = (int*)(ws + 21135360);

  prep_w_kernel<<<dim3(2048), 256, 0, stream>>>(emb, (unsigned int*)q0w,
                                                (unsigned int*)q1w, wsq);
  prep_z_kernel<<<dim3(16, 4, 16), 256, 0, stream>>>(z, (unsigned int*)q0z,
                                                     (unsigned int*)q1z);
  gemm_argmin_kernel<<<dim3(64, 128), 256, 0, stream>>>(q0z, q1z, q0w, q1w, wsq,
                                                        partials);
  reduce_top2_kernel<<<dim3(64), 256, 0, stream>>>(partials, cand);
  rescore_kernel<<<dim3(4096), 256, 0, stream>>>(cand, z, emb, ids);
  gather_kernel<<<dim3(16, 32), 256, 0, stream>>>(ids, emb, out);
}

// Round 4
// 217.347 us; speedup vs baseline: 1.7098x; 1.6162x over previous
//
#include <hip/hip_runtime.h>
#include <stdint.h>

#define DIM 256
#define NEMB 8192
#define NTOK 16384
#define HW 1024

typedef __attribute__((ext_vector_type(4))) int int4v;

// ---- helpers ----
__device__ __forceinline__ void async_cp16(void* lds, const void* g) {
  __builtin_amdgcn_global_load_lds(
      (const __attribute__((address_space(1))) unsigned int*)g,
      (__attribute__((address_space(3))) unsigned int*)lds, 16, 0, 0);
}
// x ~ s*(q0 + q1/128), s = 1/20
__device__ __forceinline__ int q0_of(float x) {
  int q = __float2int_rn(x * 20.0f);
  return q > 127 ? 127 : (q < -127 ? -127 : q);
}
__device__ __forceinline__ int q1_of(float x, int q0) {
  float e = x * 20.0f - (float)q0;
  int q = __float2int_rn(e * 128.0f);
  return q > 127 ? 127 : (q < -127 ? -127 : q);
}
__device__ __forceinline__ unsigned int pack4(int a, int b, int c, int d) {
  return (unsigned int)(a & 0xff) | ((unsigned int)(b & 0xff) << 8) |
         ((unsigned int)(c & 0xff) << 16) | ((unsigned int)(d & 0xff) << 24);
}

// ---- kernel 1: quantize emb table to int8 q0/q1 + scaled int row sumsq ----
// iwsq2 = rint(wsq*25600) + 8192  (SC units = 1/25600, +bias)
__global__ __launch_bounds__(256) void prep_w_kernel(
    const float* __restrict__ emb, unsigned int* __restrict__ q0w,
    unsigned int* __restrict__ q1w, int* __restrict__ iwsq2) {
  int lane = threadIdx.x & 63;
  int row = blockIdx.x * 4 + (threadIdx.x >> 6);
  const float4 v = *(const float4*)(emb + (size_t)row * DIM + lane * 4);
  float s = v.x * v.x + v.y * v.y + v.z * v.z + v.w * v.w;
  int a0 = q0_of(v.x), b0 = q0_of(v.y), c0 = q0_of(v.z), d0 = q0_of(v.w);
  q0w[row * (DIM / 4) + lane] = pack4(a0, b0, c0, d0);
  q1w[row * (DIM / 4) + lane] =
      pack4(q1_of(v.x, a0), q1_of(v.y, b0), q1_of(v.z, c0), q1_of(v.w, d0));
#pragma unroll
  for (int off = 32; off > 0; off >>= 1) s += __shfl_xor(s, off, 64);
  if (lane == 0) iwsq2[row] = (int)rintf(s * 25600.0f) + 8192;
}

// ---- kernel 2: transpose z [B,D,HW] -> token-major [N,D] int8 q0/q1 ----
__global__ __launch_bounds__(256) void prep_z_kernel(
    const float* __restrict__ z, unsigned int* __restrict__ q0z,
    unsigned int* __restrict__ q1z) {
  __shared__ float tile[64][65];
  int b = blockIdx.x, d0 = blockIdx.y * 64, hw0 = blockIdx.z * 64;
  int tid = threadIdx.x;
  int lane = tid & 63, grp = tid >> 6;
  const float* src = z + (size_t)b * DIM * HW + hw0 + lane;
#pragma unroll
  for (int i = 0; i < 16; i++) {
    int dl = grp + i * 4;
    tile[dl][lane] = src[(size_t)(d0 + dl) * HW];  // coalesced along hw
  }
  __syncthreads();
  int dq = tid & 15;  // covers 4 d's
#pragma unroll
  for (int p = 0; p < 4; p++) {
    int n = (tid >> 4) + p * 16;  // hw_local
    float x0 = tile[dq * 4 + 0][n], x1 = tile[dq * 4 + 1][n];
    float x2 = tile[dq * 4 + 2][n], x3 = tile[dq * 4 + 3][n];
    int a0 = q0_of(x0), b0 = q0_of(x1), c0 = q0_of(x2), e0 = q0_of(x3);
    size_t off = (size_t)(b * HW + hw0 + n) * (DIM / 4) + (d0 >> 2) + dq;
    q0z[off] = pack4(a0, b0, c0, e0);
    q1z[off] = pack4(q1_of(x0, a0), q1_of(x1, b0), q1_of(x2, c0), q1_of(x3, e0));
  }
}

// ---- kernel 3: persistent k-inner GEMM + packed-u32 top-2 ----
// block = 128 tokens x one 4096-code half; 64 iters of 64-code tiles.
// acc = 128*q0z.q0w + q0z.q1w + q1z.q0w  (per iter, fresh);
// score_int = iwsq2 - acc; pack = ((clamp(score)>>6)<<13) | idx13
__global__ __launch_bounds__(512, 2) void gemm_topk_kernel(
    const signed char* __restrict__ q0z, const signed char* __restrict__ q1z,
    const signed char* __restrict__ q0w, const signed char* __restrict__ q1w,
    const int* __restrict__ iwsq2, uint2* __restrict__ partials) {
  __shared__ __align__(16) signed char sB0[2][64 * 256];  // q0w tile, dbuf
  __shared__ __align__(16) signed char sB1[2][64 * 256];  // q1w tile, dbuf

  const int tg = blockIdx.x;     // 0..127 token group
  const int khalf = blockIdx.y;  // 0..1 code half
  const int tid = threadIdx.x;
  const int lane = tid & 63, w = tid >> 6;
  const int wm = w >> 1, wt = w & 1;  // 4 token-rows x 2 code-cols of waves
  const int c = lane & 15, quad = lane >> 4;
  const int n0 = tg * 128;
  const int k0g = khalf * 4096;

  // A fragments: global -> registers, once. A[m=lane&15][k=quad*16+j]
  int4v af0[2][4], af1[2][4];
#pragma unroll
  for (int tm = 0; tm < 2; tm++) {
    const size_t row = (size_t)(n0 + wm * 32 + tm * 16 + c) * DIM;
#pragma unroll
    for (int s = 0; s < 4; s++) {
      af0[tm][s] = *(const int4v*)(q0z + row + s * 64 + quad * 16);
      af1[tm][s] = *(const int4v*)(q1z + row + s * 64 + quad * 16);
    }
  }

  // stage B tile for iter 0 (swizzle on SOURCE, LDS dest linear in lane)
#pragma unroll
  for (int j = 0; j < 2; j++) {
    int ch = tid + j * 512;  // 0..1023
    int row = ch >> 4;
    int cl = (ch & 15) ^ (row & 7);
    async_cp16(&sB0[0][ch * 16], q0w + (size_t)(k0g + row) * DIM + cl * 16);
    async_cp16(&sB1[0][ch * 16], q1w + (size_t)(k0g + row) * DIM + cl * 16);
  }
  __syncthreads();

  unsigned int m1[8], m2[8];
#pragma unroll
  for (int i = 0; i < 8; i++) { m1[i] = 0xFFFFFFFFu; m2[i] = 0xFFFFFFFFu; }

  unsigned int idxA = (unsigned)((khalf << 12) | (wt * 32 + c));
  unsigned int idxB = idxA + 16;
  const int4v zero = {0, 0, 0, 0};

#pragma unroll 2
  for (int it = 0; it < 64; it++) {
    const int buf = it & 1;
    // stage next tile into the other buffer (last iter: re-stage, harmless)
    {
      const int itn = (it + 1 < 64) ? it + 1 : 63;
      const int nb = buf ^ 1;
#pragma unroll
      for (int j = 0; j < 2; j++) {
        int ch = tid + j * 512;
        int row = ch >> 4;
        int cl = (ch & 15) ^ (row & 7);
        async_cp16(&sB0[nb][ch * 16],
                   q0w + (size_t)(k0g + itn * 64 + row) * DIM + cl * 16);
        async_cp16(&sB1[nb][ch * 16],
                   q1w + (size_t)(k0g + itn * 64 + row) * DIM + cl * 16);
      }
    }
    // per-iter row sumsq (global, 16-lane broadcast, L1-hot)
    const int iw0 = iwsq2[k0g + it * 64 + wt * 32 + c];
    const int iw1 = iwsq2[k0g + it * 64 + wt * 32 + 16 + c];
    // B fragments from LDS (Bq0 shared by P00 & P10)
    int4v b0[2][4], b1[2][4];
#pragma unroll
    for (int tn = 0; tn < 2; tn++) {
      const int row = wt * 32 + tn * 16 + c;
#pragma unroll
      for (int s = 0; s < 4; s++) {
        const int pos = (s * 4 + quad) ^ (c & 7);  // row&7 == c&7
        b0[tn][s] = *(const int4v*)(&sB0[buf][row * 256 + pos * 16]);
        b1[tn][s] = *(const int4v*)(&sB1[buf][row * 256 + pos * 16]);
      }
    }
    int4v acc[2][2];
#pragma unroll
    for (int tm = 0; tm < 2; tm++) {
#pragma unroll
      for (int tn = 0; tn < 2; tn++) {
        int4v a = __builtin_amdgcn_mfma_i32_16x16x64_i8(af0[tm][0], b0[tn][0],
                                                        zero, 0, 0, 0);
#pragma unroll
        for (int s = 1; s < 4; s++)
          a = __builtin_amdgcn_mfma_i32_16x16x64_i8(af0[tm][s], b0[tn][s], a,
                                                    0, 0, 0);
#pragma unroll
        for (int r = 0; r < 4; r++) a[r] <<= 7;  // 128*P00
#pragma unroll
        for (int s = 0; s < 4; s++)
          a = __builtin_amdgcn_mfma_i32_16x16x64_i8(af0[tm][s], b1[tn][s], a,
                                                    0, 0, 0);
#pragma unroll
        for (int s = 0; s < 4; s++)
          a = __builtin_amdgcn_mfma_i32_16x16x64_i8(af1[tm][s], b0[tn][s], a,
                                                    0, 0, 0);
        acc[tm][tn] = a;
      }
    }
    // epilogue: packed-u32 top-2 insert (C/D: col=lane&15, row=quad*4+r)
#pragma unroll
    for (int tm = 0; tm < 2; tm++) {
#pragma unroll
      for (int r = 0; r < 4; r++) {
        unsigned int s0 = (unsigned int)(iw0 - acc[tm][0][r]);
        unsigned int s1 = (unsigned int)(iw1 - acc[tm][1][r]);
        s0 = s0 < 0x2000000u ? s0 : 0x1FFFFFFu;  // v_min_u32 clamp
        s1 = s1 < 0x2000000u ? s1 : 0x1FFFFFFu;
        unsigned int p0 = ((s0 << 7) & 0xFFFFE000u) | idxA;
        unsigned int p1 = ((s1 << 7) & 0xFFFFE000u) | idxB;
        unsigned int v = p0 < p1 ? p0 : p1;
        const int ix = tm * 4 + r;
        unsigned int lo = v < m1[ix] ? v : m1[ix];
        unsigned int hi = v < m1[ix] ? m1[ix] : v;
        m2[ix] = m2[ix] < hi ? m2[ix] : hi;
        m1[ix] = lo;
      }
    }
    idxA += 64;
    idxB += 64;
    __syncthreads();  // drains next-tile loads (in flight all compute phase)
  }

  // merge top-2 across the 16 c-lanes (idx rides in low bits)
#pragma unroll
  for (int ix = 0; ix < 8; ix++) {
    unsigned int a1 = m1[ix], a2 = m2[ix];
#pragma unroll
    for (int off = 1; off < 16; off <<= 1) {
      unsigned int o1 = __shfl_xor(a1, off, 16);
      unsigned int o2 = __shfl_xor(a2, off, 16);
      unsigned int n1 = a1 < o1 ? a1 : o1;
      unsigned int hi = a1 < o1 ? o1 : a1;
      unsigned int l2 = a2 < o2 ? a2 : o2;
      a2 = hi < l2 ? hi : l2;
      a1 = n1;
    }
    m1[ix] = a1;
    m2[ix] = a2;
  }
  if (c == 0) {
#pragma unroll
    for (int tm = 0; tm < 2; tm++) {
#pragma unroll
      for (int r = 0; r < 4; r++) {
        int token = tg * 128 + wm * 32 + tm * 16 + quad * 4 + r;
        partials[(size_t)(khalf * 2 + wt) * NTOK + token] =
            make_uint2(m1[tm * 4 + r], m2[tm * 4 + r]);
      }
    }
  }
}

// ---- kernel 4: exact fp64 rescore of all 8 candidates ----
__global__ __launch_bounds__(256) void rescore_kernel(
    const uint2* __restrict__ partials, const float* __restrict__ z,
    const float* __restrict__ emb, int* __restrict__ ids) {
  int w = threadIdx.x >> 6, lane = threadIdx.x & 63;
  int token = blockIdx.x * 4 + w;
  int b = token >> 10, hw = token & (HW - 1);
  unsigned int cand[8];
#pragma unroll
  for (int q = 0; q < 4; q++) {
    uint2 p = partials[(size_t)q * NTOK + token];
    cand[q * 2] = p.x & 0x1FFFu;
    cand[q * 2 + 1] = p.y & 0x1FFFu;
  }
  const float* zb = z + (size_t)b * DIM * HW + hw;
  float zv[4];
#pragma unroll
  for (int j = 0; j < 4; j++) zv[j] = zb[(size_t)(lane + j * 64) * HW];
  double best = 1e300;
  int bid = NEMB;
#pragma unroll
  for (int q = 0; q < 8; q++) {
    const float* e = emb + (size_t)cand[q] * DIM;
    double s = 0.0;
#pragma unroll
    for (int j = 0; j < 4; j++) {
      double wv = (double)e[lane + j * 64];
      s += wv * (wv - 2.0 * (double)zv[j]);
    }
#pragma unroll
    for (int off = 32; off > 0; off >>= 1) s += __shfl_xor(s, off, 64);
    int id = (int)cand[q];
    if (s < best || (s == best && id < bid)) {
      best = s;
      bid = id;
    }
  }
  if (lane == 0) ids[token] = bid;
}

// ---- kernel 5: gather emb rows, transpose to [B,D,H,W] via LDS ----
__global__ __launch_bounds__(256) void gather_kernel(
    const int* __restrict__ ids, const float* __restrict__ emb,
    float* __restrict__ out) {
  __shared__ float tile[32][257];
  __shared__ int sid[32];
  int b = blockIdx.x;
  int hw0 = blockIdx.y * 32;
  int tid = threadIdx.x;
  if (tid < 32) sid[tid] = ids[b * HW + hw0 + tid];
  __syncthreads();
  for (int i = 0; i < 32; i++)
    tile[i][tid] = emb[(size_t)sid[i] * DIM + tid];  // coalesced 1KB row loads
  __syncthreads();
  int h = tid & 31, dg = tid >> 5;
  for (int i = 0; i < 32; i++) {
    int d = i * 8 + dg;
    out[(size_t)b * DIM * HW + (size_t)d * HW + hw0 + h] = tile[h][d];
  }
}

extern "C" void kernel_launch(void* const* d_in, const int* in_sizes, int n_in,
                              void* d_out, int out_size, void* d_ws, size_t ws_size,
                              hipStream_t stream) {
  const float* z = (const float*)d_in[0];    // [16,256,32,32]
  const float* emb = (const float*)d_in[1];  // [8192,256]
  float* out = (float*)d_out;
  char* ws = (char*)d_ws;

  // q0z/q1z live in d_out (8 MB of 16) — dead until gather overwrites it.
  signed char* q0z = (signed char*)d_out;
  signed char* q1z = (signed char*)((char*)d_out + 4194304);

  // ws: q0w 2M | q1w 2M | iwsq2 32K | partials 512K | ids 64K
  signed char* q0w = (signed char*)(ws);
  signed char* q1w = (signed char*)(ws + 2097152);
  int* iwsq2 = (int*)(ws + 4194304);
  uint2* partials = (uint2*)(ws + 4227072);
  int* ids = (int*)(ws + 4751360);

  prep_w_kernel<<<dim3(2048), 256, 0, stream>>>(emb, (unsigned int*)q0w,
                                                (unsigned int*)q1w, iwsq2);
  prep_z_kernel<<<dim3(16, 4, 16), 256, 0, stream>>>(z, (unsigned int*)q0z,
                                                     (unsigned int*)q1z);
  gemm_topk_kernel<<<dim3(128, 2), 512, 0, stream>>>(q0z, q1z, q0w, q1w, iwsq2,
                                                     partials);
  rescore_kernel<<<dim3(4096), 256, 0, stream>>>(partials, z, emb, ids);
  gather_kernel<<<dim3(16, 32), 256, 0, stream>>>(ids, emb, out);
}